// Round 1
// baseline (487.357 us; speedup 1.0000x reference)
//
#include <hip/hip_runtime.h>

#define LQ 384
#define DF 64
#define NWIN 16
#define PERW 15      // NG + NF
#define STEPW 16     // 1 + NG + NF
#define NPAIR 240    // NWIN * PERW
#define BSTRIDE 65   // 64 + 1 padding: stride mod 32 == 1 -> conflict-free-ish
#define BIGV 1e9f

// ---------------------------------------------------------------------------
// Kernel 1: one block per pair; full soft-DTW DP over anti-diagonals.
// Thread tid owns DP row r = tid+1. A-row in registers, B in padded LDS.
// ---------------------------------------------------------------------------
__global__ __launch_bounds__(LQ) void sdtw_kernel(const float* __restrict__ data,
                                                  const int* __restrict__ lens,
                                                  float* __restrict__ dist) {
  const int p = blockIdx.x;          // pair id 0..239
  const int w = p / PERW;
  const int o = p - w * PERW;
  const int aRow = w * STEPW;
  const int bRow = aRow + 1 + o;
  const int la = lens[aRow];
  const int lb = lens[bRow];
  const int tid = threadIdx.x;

  __shared__ float Bsh[LQ * BSTRIDE];   // 99840 B
  __shared__ float sqB[LQ];
  __shared__ float Rbuf[3][LQ + 1];     // rotating anti-diagonals

  const float* __restrict__ Aptr = data + (size_t)aRow * LQ * DF;
  const float* __restrict__ Bptr = data + (size_t)bRow * LQ * DF;

  // Stage B into LDS (coalesced global, ~2-way LDS bank alias max).
  for (int idx = tid; idx < LQ * DF; idx += LQ) {
    int row = idx >> 6;
    int col = idx & 63;
    Bsh[row * BSTRIDE + col] = Bptr[idx];
  }

  // A row -> registers (float4 loads).
  float a[DF];
  {
    const float4* A4 = (const float4*)(Aptr + (size_t)tid * DF);
#pragma unroll
    for (int k = 0; k < DF / 4; ++k) {
      float4 v = A4[k];
      a[4 * k + 0] = v.x; a[4 * k + 1] = v.y;
      a[4 * k + 2] = v.z; a[4 * k + 3] = v.w;
    }
  }
  float sqA = 0.f;
#pragma unroll
  for (int k = 0; k < DF; ++k) sqA = fmaf(a[k], a[k], sqA);

  __syncthreads();  // Bsh ready

  // Row norms of B.
  {
    float s = 0.f;
    const float* brow = &Bsh[tid * BSTRIDE];
#pragma unroll
    for (int k = 0; k < DF; ++k) s = fmaf(brow[k], brow[k], s);
    sqB[tid] = s;
  }

  // Init diagonals: Rbuf[0] = diag(-1) = all BIG; Rbuf[1] = diag0 = [0, BIG...].
  for (int idx = tid; idx <= LQ; idx += LQ) {
    Rbuf[0][idx] = BIGV;
    Rbuf[1][idx] = (idx == 0) ? 0.f : BIGV;
  }
  __syncthreads();

  const int r = tid + 1;           // 1-based DP row this thread owns
  const int dmax = la + lb;
  float val = BIGV;

  for (int d = 1; d <= dmax; ++d) {
    float* newb        = Rbuf[(d + 1) % 3];
    const float* prev  = Rbuf[d % 3];
    const float* prev2 = Rbuf[(d - 1) % 3];
    const int j = d - r;           // 1-based DP col for this thread on diag d
    val = BIGV;
    if (r <= la && j >= 1 && j <= lb) {
      const float* brow = &Bsh[(j - 1) * BSTRIDE];
      float dot = 0.f;
#pragma unroll
      for (int k = 0; k < DF; ++k) dot = fmaf(a[k], brow[k], dot);
      float Dij = sqA + sqB[j - 1] - 2.f * dot;
      float x0 = prev2[r - 1];     // (i-1, j-1)
      float x1 = prev[r - 1];      // (i-1, j)
      float x2 = prev[r];          // (i,   j-1)
      float m = fminf(x0, fminf(x1, x2));
      float s = expf((m - x0) * 0.2f) + expf((m - x1) * 0.2f) + expf((m - x2) * 0.2f);
      val = Dij + m - 5.0f * logf(s);
    }
    newb[r] = val;
    if (tid == 0) newb[0] = BIGV;
    __syncthreads();
  }

  // Thread owning row la computed R[la][lb] on the final diagonal.
  if (tid == la - 1) {
    dist[p] = val / (float)dmax;
  }
}

// ---------------------------------------------------------------------------
// Kernel 2: tiny loss reduction over 16 windows.
// ---------------------------------------------------------------------------
__device__ __forceinline__ float median5(const float* v) {
  // rank-2 order statistic with stable tie-break (matches np.median of 5)
#pragma unroll
  for (int i = 0; i < 5; ++i) {
    int c = 0;
#pragma unroll
    for (int j = 0; j < 5; ++j)
      c += (v[j] < v[i]) || ((v[j] == v[i]) && (j < i));
    if (c == 2) return v[i];
  }
  return v[0];
}

__global__ void loss_kernel(const float* __restrict__ dist, float* __restrict__ out) {
  __shared__ float acc[NWIN];
  const int w = threadIdx.x;
  if (w < NWIN) {
    float dg[5], dn[10];
#pragma unroll
    for (int g = 0; g < 5; ++g)  dg[g] = dist[w * PERW + g];
#pragma unroll
    for (int n = 0; n < 10; ++n) dn[n] = dist[w * PERW + 5 + n];

    float lk = 0.f; int nz = 0;
#pragma unroll
    for (int g = 0; g < 5; ++g)
#pragma unroll
      for (int n = 0; n < 10; ++n) {
        float t = dg[g] + 1.0f - dn[n];
        if (t > 0.f) { lk += t; ++nz; }
      }
    float lv = lk / (1.0f + (float)nz);

    float sp = 0.f;
#pragma unroll
    for (int g = 0; g < 5; ++g) sp += dg[g];
    float only_pos = sp * (0.01f / 5.0f);   // LAM / NG

    float mg = median5(dg);
    float ms = median5(dn);                 // median of dn[0:5]

    int err = 0;
#pragma unroll
    for (int g = 0; g < 5; ++g) {
      err += ((dg[g] < mg) && (dn[g] < mg));
      err += ((dg[g] > ms) && (dn[g] > ms));
      err += ((dg[g] < mg) && (dn[5 + g] < mg));
      err += ((dg[g] > ms) && (dn[5 + g] > ms));
    }
    float offset = (float)err * (1.0f / 50.0f);  // / (NF*NG)

    acc[w] = lv + only_pos + offset;             // ALPHA = 1
  }
  __syncthreads();
  if (w == 0) {
    float s = 0.f;
#pragma unroll
    for (int i = 0; i < NWIN; ++i) s += acc[i];
    out[0] = s / (float)NWIN;
  }
}

// ---------------------------------------------------------------------------
extern "C" void kernel_launch(void* const* d_in, const int* in_sizes, int n_in,
                              void* d_out, int out_size, void* d_ws, size_t ws_size,
                              hipStream_t stream) {
  const float* data = (const float*)d_in[0];
  const int* lens   = (const int*)d_in[1];
  float* dist = (float*)d_ws;   // 240 floats of scratch

  sdtw_kernel<<<NPAIR, LQ, 0, stream>>>(data, lens, dist);
  loss_kernel<<<1, 64, 0, stream>>>(dist, (float*)d_out);
}

// Round 2
// 459.470 us; speedup vs baseline: 1.0607x; 1.0607x over previous
//
#include <hip/hip_runtime.h>

#define LQ 384
#define DF 64
#define NWIN 16
#define PERW 15      // NG + NF
#define STEPW 16     // 1 + NG + NF
#define NPAIR 240    // NWIN * PERW
#define BIGV 1e9f
#define NWAVE 6
#define PW 32        // panel width (cols per round)
#define NPANEL 12    // 384 / PW
#define NROUND 17    // NPANEL + NWAVE - 1
#define BST 66       // B LDS row stride (floats): 66-1 odd -> bank-spread; even -> b64 aligned
#define DST 36       // D-tile row stride (floats): 36-1 odd -> bank-spread; mult of 4 -> b128 aligned
// exp((m-x)/5) = exp2((m-x)*C2); 5*log(s) = L2C*log2(s)
#define C2  0.28853900817779268f   // 1/(5*ln2)
#define L2C 3.4657359027997265f    // 5*ln2

__device__ __forceinline__ float fexp2(float x) { return __builtin_amdgcn_exp2f(x); }
__device__ __forceinline__ float flog2(float x) { return __builtin_amdgcn_logf(x); }

// ---------------------------------------------------------------------------
// One block per pair. 6 waves; wave w owns DP rows 64w+1..64w+64 (lane = local
// row). Panels of 32 cols; wave w processes panel p = round - w (software
// pipeline across waves, one barrier per round). Per round: register-tiled
// GEMM computes the wave's 64x32 D-tile into LDS, then 96 in-wave anti-
// diagonal steps with 1 shuffle/step (no barriers inside a round).
// ---------------------------------------------------------------------------
__global__ __launch_bounds__(LQ) void sdtw_kernel(const float* __restrict__ data,
                                                  const int* __restrict__ lens,
                                                  float* __restrict__ dist) {
  __shared__ __align__(16) float Bsh[LQ * BST];          // 101376 B
  __shared__ __align__(16) float Dt[NWAVE][64 * DST];    // 55296 B
  __shared__ __align__(16) float sqA[LQ];                // 1536 B
  __shared__ __align__(16) float sqB[LQ];                // 1536 B
  __shared__ __align__(16) float bnd[NWAVE][2][36];      // 1728 B  (total 161472 <= 163840)

  const int p_id = blockIdx.x;
  const int wwin = p_id / PERW;
  const int o = p_id - wwin * PERW;
  const int aRow = wwin * STEPW;
  const int bRow = aRow + 1 + o;
  const int la = lens[aRow];
  const int lb = lens[bRow];
  const int tid = threadIdx.x;
  const int w = tid >> 6;       // wave id 0..5
  const int lane = tid & 63;

  const float* __restrict__ A  = data + (size_t)aRow * LQ * DF;
  const float* __restrict__ Bp = data + (size_t)bRow * LQ * DF;

  // ---- stage B into LDS (row stride BST), b64 writes (BST even) ----
  {
    const float4* B4 = (const float4*)Bp;
    for (int q = tid; q < LQ * 16; q += LQ) {
      float4 v = B4[q];                       // coalesced global
      int row = q >> 4, c4 = (q & 15) << 2;
      float* dst = &Bsh[row * BST + c4];
      ((float2*)dst)[0] = make_float2(v.x, v.y);
      ((float2*)dst)[1] = make_float2(v.z, v.w);
    }
  }
  // ---- sqA: thread tid handles A row tid ----
  {
    const float4* A4 = (const float4*)(A + (size_t)tid * DF);
    float s = 0.f;
#pragma unroll
    for (int k = 0; k < 16; ++k) {
      float4 v = A4[k];
      s = fmaf(v.x, v.x, s); s = fmaf(v.y, v.y, s);
      s = fmaf(v.z, v.z, s); s = fmaf(v.w, v.w, s);
    }
    sqA[tid] = s;
  }
  __syncthreads();
  // ---- sqB from staged LDS ----
  {
    float s = 0.f;
    const float2* row = (const float2*)&Bsh[tid * BST];
#pragma unroll
    for (int k = 0; k < 32; ++k) { float2 v = row[k]; s = fmaf(v.x, v.x, s); s = fmaf(v.y, v.y, s); }
    sqB[tid] = s;
  }

  // extraction target: R[la][lb] computed by wave wt, lane it, panel pt, step tstar
  const int wt = (la - 1) >> 6;
  const int it = (la - 1) & 63;
  const int pt = (lb - 1) >> 5;
  const int tstar = it + ((lb - 1) & 31);
  const int rstar = wt + pt;
  const float invLen = 1.0f / (float)(la + lb);

  float leftR = BIGV;               // R[row][panel_start-1]; col 0 => BIG
  float* DtW = &Dt[w][0];
  const int rg = lane >> 3, cg = lane & 7;   // GEMM tile coords: 8 rows x 4 cols per lane

  for (int r = 0; r < NROUND; ++r) {
    __syncthreads();                // protects bnd double-buffer across waves
    const int p = r - w;
    if ((unsigned)p < (unsigned)NPANEL) {
      // ================= GEMM: D-tile rows 64w..64w+63, cols 32p..32p+31 =====
      float acc[8][4];
#pragma unroll
      for (int a_ = 0; a_ < 8; ++a_)
#pragma unroll
        for (int b_ = 0; b_ < 4; ++b_) acc[a_][b_] = 0.f;
      const float4* A4 = (const float4*)(A + (size_t)(64 * w + 8 * rg) * DF);
      const float* Bbase = &Bsh[(PW * p + 4 * cg) * BST];
#pragma unroll
      for (int kk = 0; kk < 16; ++kk) {
        float4 av[8];
#pragma unroll
        for (int rr = 0; rr < 8; ++rr) av[rr] = A4[rr * 16 + kk];   // L1/L2-cached
        float2 bv[4][2];
#pragma unroll
        for (int cc = 0; cc < 4; ++cc) {
          const float2* bp2 = (const float2*)&Bbase[cc * BST + 4 * kk];
          bv[cc][0] = bp2[0]; bv[cc][1] = bp2[1];
        }
#pragma unroll
        for (int rr = 0; rr < 8; ++rr)
#pragma unroll
          for (int cc = 0; cc < 4; ++cc) {
            acc[rr][cc] = fmaf(av[rr].x, bv[cc][0].x, acc[rr][cc]);
            acc[rr][cc] = fmaf(av[rr].y, bv[cc][0].y, acc[rr][cc]);
            acc[rr][cc] = fmaf(av[rr].z, bv[cc][1].x, acc[rr][cc]);
            acc[rr][cc] = fmaf(av[rr].w, bv[cc][1].y, acc[rr][cc]);
          }
      }
      {
        float4 sb = *(const float4*)&sqB[PW * p + 4 * cg];
#pragma unroll
        for (int rr = 0; rr < 8; ++rr) {
          float sa = sqA[64 * w + 8 * rg + rr];
          float4 ov;
          ov.x = sa + sb.x - 2.f * acc[rr][0];
          ov.y = sa + sb.y - 2.f * acc[rr][1];
          ov.z = sa + sb.z - 2.f * acc[rr][2];
          ov.w = sa + sb.w - 2.f * acc[rr][3];
          *(float4*)&DtW[(8 * rg + rr) * DST + 4 * cg] = ov;  // conflict-free
        }
      }
      __builtin_amdgcn_sched_barrier(0);   // keep D reads after D writes

      // ================= DP: 96 anti-diagonal steps, no barriers =============
      float* bndR = &bnd[w][r & 1][0];
      const int wn = (w + 1 < NWAVE) ? (w + 1) : 0;
      float* bndW = &bnd[wn][(r + 1) & 1][0];
      const bool wr63 = (lane == 63) && (w + 1 < NWAVE);
      if (wr63) bndW[0] = leftR;          // R[64(w+1)][32p]

      // 2-deep register prefetch of D (addr = 35*lane + t: 2-way banks, free)
      float d0, d1;
      {
        int j0c = 0 - lane; j0c = j0c < 0 ? 0 : j0c;
        int j1c = 1 - lane; j1c = j1c < 0 ? 0 : j1c;
        d0 = DtW[lane * DST + j0c];
        d1 = DtW[lane * DST + j1c];
      }
      float cur = leftR;     // R[row][j-1] (left)
      float s2  = leftR;     // rolling diag = previous step's shuffled cur
      float bq0[4], bq1[4];  // boundary-row quads (lane 0 of waves >0)
      if (w > 0) {
        float4 q0 = *(const float4*)&bndR[0];
        float4 q1 = *(const float4*)&bndR[4];
        bq0[0]=q0.x; bq0[1]=q0.y; bq0[2]=q0.z; bq0[3]=q0.w;
        bq1[0]=q1.x; bq1[1]=q1.y; bq1[2]=q1.z; bq1[3]=q1.w;
      }
      const bool extw = (w == wt) && (r == rstar);

#define STEP(T, BDIAG, BUP) do {                                            \
        float s1 = __shfl_up(cur, 1);                                       \
        if (lane == 0) {                                                    \
          if (w == 0) { s1 = BIGV; s2 = (p == 0 && (T) == 0) ? 0.f : BIGV; }\
          else        { s1 = (BUP); s2 = (BDIAG); }                         \
        }                                                                   \
        int jl = (T) - lane;                                                \
        bool valid = (unsigned)jl < 32u;                                    \
        float dv = d0; d0 = d1;                                             \
        { int jc = (T) + 2 - lane; jc = jc < 0 ? 0 : (jc > 31 ? 31 : jc);   \
          d1 = DtW[lane * DST + jc]; }                                      \
        float m = fminf(s2, fminf(s1, cur));                                \
        float e0 = fexp2((m - s2)  * C2);                                   \
        float e1 = fexp2((m - s1)  * C2);                                   \
        float e2 = fexp2((m - cur) * C2);                                   \
        float val = dv + m - L2C * flog2(e0 + e1 + e2);                     \
        s2 = s1;                                                            \
        if (valid) {                                                        \
          cur = val;                                                        \
          if (wr63) bndW[jl + 1] = val;                                     \
          if (extw && (T) == tstar && lane == it) dist[p_id] = val * invLen;\
        }                                                                   \
      } while (0)

      for (int tq = 0; tq < 24; ++tq) {
        const int tb = tq * 4;
        float bq2[4];
        if (w > 0) {
          int off = tb + 8; off = off > 32 ? 32 : off;     // clamp inside bnd[36]
          float4 q = *(const float4*)&bndR[off];
          bq2[0]=q.x; bq2[1]=q.y; bq2[2]=q.z; bq2[3]=q.w;
        }
        STEP(tb + 0, bq0[0], bq0[1]);
        STEP(tb + 1, bq0[1], bq0[2]);
        STEP(tb + 2, bq0[2], bq0[3]);
        STEP(tb + 3, bq0[3], bq1[0]);
        bq0[0]=bq1[0]; bq0[1]=bq1[1]; bq0[2]=bq1[2]; bq0[3]=bq1[3];
        bq1[0]=bq2[0]; bq1[1]=bq2[1]; bq1[2]=bq2[2]; bq1[3]=bq2[3];
      }
#undef STEP
      leftR = cur;            // R[row][32p+32] -> next panel's left boundary
    }
  }
}

// ---------------------------------------------------------------------------
// Loss reduction over 16 windows (validated round 1).
// ---------------------------------------------------------------------------
__device__ __forceinline__ float median5(const float* v) {
#pragma unroll
  for (int i = 0; i < 5; ++i) {
    int c = 0;
#pragma unroll
    for (int j = 0; j < 5; ++j)
      c += (v[j] < v[i]) || ((v[j] == v[i]) && (j < i));
    if (c == 2) return v[i];
  }
  return v[0];
}

__global__ void loss_kernel(const float* __restrict__ dist, float* __restrict__ out) {
  __shared__ float acc[NWIN];
  const int w = threadIdx.x;
  if (w < NWIN) {
    float dg[5], dn[10];
#pragma unroll
    for (int g = 0; g < 5; ++g)  dg[g] = dist[w * PERW + g];
#pragma unroll
    for (int n = 0; n < 10; ++n) dn[n] = dist[w * PERW + 5 + n];

    float lk = 0.f; int nz = 0;
#pragma unroll
    for (int g = 0; g < 5; ++g)
#pragma unroll
      for (int n = 0; n < 10; ++n) {
        float t = dg[g] + 1.0f - dn[n];
        if (t > 0.f) { lk += t; ++nz; }
      }
    float lv = lk / (1.0f + (float)nz);

    float sp = 0.f;
#pragma unroll
    for (int g = 0; g < 5; ++g) sp += dg[g];
    float only_pos = sp * (0.01f / 5.0f);

    float mg = median5(dg);
    float ms = median5(dn);

    int err = 0;
#pragma unroll
    for (int g = 0; g < 5; ++g) {
      err += ((dg[g] < mg) && (dn[g] < mg));
      err += ((dg[g] > ms) && (dn[g] > ms));
      err += ((dg[g] < mg) && (dn[5 + g] < mg));
      err += ((dg[g] > ms) && (dn[5 + g] > ms));
    }
    float offset = (float)err * (1.0f / 50.0f);

    acc[w] = lv + only_pos + offset;
  }
  __syncthreads();
  if (w == 0) {
    float s = 0.f;
#pragma unroll
    for (int i = 0; i < NWIN; ++i) s += acc[i];
    out[0] = s / (float)NWIN;
  }
}

// ---------------------------------------------------------------------------
extern "C" void kernel_launch(void* const* d_in, const int* in_sizes, int n_in,
                              void* d_out, int out_size, void* d_ws, size_t ws_size,
                              hipStream_t stream) {
  const float* data = (const float*)d_in[0];
  const int* lens   = (const int*)d_in[1];
  float* dist = (float*)d_ws;

  sdtw_kernel<<<NPAIR, LQ, 0, stream>>>(data, lens, dist);
  loss_kernel<<<1, 64, 0, stream>>>(dist, (float*)d_out);
}

// Round 3
// 295.103 us; speedup vs baseline: 1.6515x; 1.5570x over previous
//
#include <hip/hip_runtime.h>

#define LQ 384
#define DF 64
#define NWIN 16
#define PERW 15      // NG + NF
#define STEPW 16     // 1 + NG + NF
#define NPAIR 240    // NWIN * PERW
#define BIGV 1e9f
#define NWAVE 6
#define PW 32        // panel width (cols per round)
#define NPANEL 12    // 384 / PW
#define NROUND 17    // NPANEL + NWAVE - 1
#define BST 66       // B LDS row stride (floats)
#define DCS 68       // D-tile COLUMN stride (col-major [32 cols][68]): mult of 4,
                     // stores 8/bank (=b128 min), diag reads bank=4T-3*lane (coprime)
#define C2  0.28853900817779268f   // 1/(5*ln2)
#define L2C 3.4657359027997265f    // 5*ln2

typedef float v2f __attribute__((ext_vector_type(2)));

__device__ __forceinline__ float fexp2(float x) { return __builtin_amdgcn_exp2f(x); }
__device__ __forceinline__ float flog2(float x) { return __builtin_amdgcn_logf(x); }

// lane l gets lane l-1's value via DPP wave_shr:1 (VALU pipe, no LDS).
// Lane 0 keeps old value (bound_ctrl=false) - always overwritten by fixup.
__device__ __forceinline__ float wshr1(float x) {
  int xi = __float_as_int(x);
  int r = __builtin_amdgcn_update_dpp(xi, xi, 0x138, 0xF, 0xF, false);
  return __int_as_float(r);
}

// ---------------------------------------------------------------------------
// One block per pair. 6 waves; wave w owns DP rows 64w+1..64w+64 (lane = local
// row). Panels of 32 cols; wave w does panel p = round - w. Per round: packed-
// f32 register GEMM -> col-major D tile in LDS -> 96 anti-diagonal DP steps
// with DPP cross-lane shift (no barriers inside a round).
// ---------------------------------------------------------------------------
__global__ __launch_bounds__(LQ, 2) void sdtw_kernel(const float* __restrict__ data,
                                                     const int* __restrict__ lens,
                                                     float* __restrict__ dist) {
  __shared__ __align__(16) float Bsh[LQ * BST];          // 101376 B
  __shared__ __align__(16) float Dt[NWAVE][32 * DCS];    // 52224 B
  __shared__ __align__(16) float sqA[LQ];                // 1536 B
  __shared__ __align__(16) float sqB[LQ];                // 1536 B
  __shared__ __align__(16) float bnd[NWAVE][2][36];      // 1728 B  (total 158400)

  const int p_id = blockIdx.x;
  const int wwin = p_id / PERW;
  const int o = p_id - wwin * PERW;
  const int aRow = wwin * STEPW;
  const int bRow = aRow + 1 + o;
  const int la = lens[aRow];
  const int lb = lens[bRow];
  const int tid = threadIdx.x;
  const int w = tid >> 6;       // wave id 0..5
  const int lane = tid & 63;

  const float* __restrict__ A  = data + (size_t)aRow * LQ * DF;
  const float* __restrict__ Bp = data + (size_t)bRow * LQ * DF;

  // ---- stage B into LDS (row stride BST) ----
  {
    const float4* B4 = (const float4*)Bp;
    for (int q = tid; q < LQ * 16; q += LQ) {
      float4 v = B4[q];
      int row = q >> 4, c4 = (q & 15) << 2;
      float* dst = &Bsh[row * BST + c4];
      ((float2*)dst)[0] = make_float2(v.x, v.y);
      ((float2*)dst)[1] = make_float2(v.z, v.w);
    }
  }
  // ---- sqA ----
  {
    const float4* A4 = (const float4*)(A + (size_t)tid * DF);
    float s = 0.f;
#pragma unroll
    for (int k = 0; k < 16; ++k) {
      float4 v = A4[k];
      s = fmaf(v.x, v.x, s); s = fmaf(v.y, v.y, s);
      s = fmaf(v.z, v.z, s); s = fmaf(v.w, v.w, s);
    }
    sqA[tid] = s;
  }
  __syncthreads();
  // ---- sqB from staged LDS ----
  {
    float s = 0.f;
    const float2* row = (const float2*)&Bsh[tid * BST];
#pragma unroll
    for (int k = 0; k < 32; ++k) { float2 v = row[k]; s = fmaf(v.x, v.x, s); s = fmaf(v.y, v.y, s); }
    sqB[tid] = s;
  }

  // extraction target: R[la][lb] at wave wt, lane it, panel pt, step tstar
  const int wt = (la - 1) >> 6;
  const int it = (la - 1) & 63;
  const int pt = (lb - 1) >> 5;
  const int tstar = it + ((lb - 1) & 31);
  const int rstar = wt + pt;
  const float invLen = 1.0f / (float)(la + lb);

  float leftR = BIGV;               // R[row][panel_start-1]; col 0 => BIG
  float* DtW = &Dt[w][0];
  const int rg = lane >> 3, cg = lane & 7;   // GEMM: 8 rows x 4 cols per lane
  const bool waveActive = (64 * w < la);     // wave's first row 64w+1 <= la

  for (int r = 0; r < NROUND; ++r) {
    __syncthreads();                // protects bnd double-buffer across waves
    const int p = r - w;
    if ((unsigned)p < (unsigned)NPANEL && waveActive && (32 * p < lb)) {
      // ===== GEMM: rows 64w..64w+63 x cols 32p..32p+31, packed f32 ==========
      v2f acc[8][4];
#pragma unroll
      for (int a_ = 0; a_ < 8; ++a_)
#pragma unroll
        for (int b_ = 0; b_ < 4; ++b_) { acc[a_][b_].x = 0.f; acc[a_][b_].y = 0.f; }
      const float4* A4 = (const float4*)(A + (size_t)(64 * w + 8 * rg) * DF);
      const float* Bbase = &Bsh[(PW * p + 4 * cg) * BST];
#pragma unroll
      for (int kk = 0; kk < 16; ++kk) {
        v2f a0[8], a1[8];
#pragma unroll
        for (int rr = 0; rr < 8; ++rr) {
          float4 v = A4[rr * 16 + kk];
          a0[rr].x = v.x; a0[rr].y = v.y; a1[rr].x = v.z; a1[rr].y = v.w;
        }
        v2f b0[4], b1[4];
#pragma unroll
        for (int cc = 0; cc < 4; ++cc) {
          b0[cc] = *(const v2f*)&Bbase[cc * BST + 4 * kk];
          b1[cc] = *(const v2f*)&Bbase[cc * BST + 4 * kk + 2];
        }
#pragma unroll
        for (int rr = 0; rr < 8; ++rr)
#pragma unroll
          for (int cc = 0; cc < 4; ++cc) {
            acc[rr][cc] = __builtin_elementwise_fma(a0[rr], b0[cc], acc[rr][cc]);
            acc[rr][cc] = __builtin_elementwise_fma(a1[rr], b1[cc], acc[rr][cc]);
          }
      }
      // ===== epilogue: D = sqA + sqB - 2*dot, store col-major ===============
      {
        float sa[8];
        *(float4*)&sa[0] = *(const float4*)&sqA[64 * w + 8 * rg];
        *(float4*)&sa[4] = *(const float4*)&sqA[64 * w + 8 * rg + 4];
        float4 sb = *(const float4*)&sqB[PW * p + 4 * cg];
        float sbv[4] = {sb.x, sb.y, sb.z, sb.w};
#pragma unroll
        for (int cc = 0; cc < 4; ++cc) {
          float4 lo, hi;
          lo.x = sa[0] + sbv[cc] - 2.f * (acc[0][cc].x + acc[0][cc].y);
          lo.y = sa[1] + sbv[cc] - 2.f * (acc[1][cc].x + acc[1][cc].y);
          lo.z = sa[2] + sbv[cc] - 2.f * (acc[2][cc].x + acc[2][cc].y);
          lo.w = sa[3] + sbv[cc] - 2.f * (acc[3][cc].x + acc[3][cc].y);
          hi.x = sa[4] + sbv[cc] - 2.f * (acc[4][cc].x + acc[4][cc].y);
          hi.y = sa[5] + sbv[cc] - 2.f * (acc[5][cc].x + acc[5][cc].y);
          hi.z = sa[6] + sbv[cc] - 2.f * (acc[6][cc].x + acc[6][cc].y);
          hi.w = sa[7] + sbv[cc] - 2.f * (acc[7][cc].x + acc[7][cc].y);
          float* dp = &DtW[(4 * cg + cc) * DCS + 8 * rg];
          *(float4*)dp = lo;
          *(float4*)(dp + 4) = hi;
        }
      }
      __builtin_amdgcn_sched_barrier(0);   // D stores before D reads

      // ===== DP: 96 anti-diagonal steps, DPP shift, no barriers =============
      float* bndR = &bnd[w][r & 1][0];
      const int wn = (w + 1 < NWAVE) ? (w + 1) : 0;
      float* bndW = &bnd[wn][(r + 1) & 1][0];
      const bool wr63 = (lane == 63) && (w + 1 < NWAVE) && (64 * (w + 1) < la);
      if (wr63) bndW[0] = leftR;          // R[64(w+1)][32p]

      // 3-deep register prefetch of D; (&31) wrap keeps banks distinct
      float d0, d1, d2;
      {
        int j0 = (0 - lane) & 31, j1 = (1 - lane) & 31, j2 = (2 - lane) & 31;
        d0 = DtW[j0 * DCS + lane];
        d1 = DtW[j1 * DCS + lane];
        d2 = DtW[j2 * DCS + lane];
      }
      float cur = leftR;     // R[row][j-1]
      float s2  = leftR;     // rolling diag
      float extv = 0.f;
      float bq0[4], bq1[4];
      if (w > 0) {
        float4 q0 = *(const float4*)&bndR[0];
        float4 q1 = *(const float4*)&bndR[4];
        bq0[0]=q0.x; bq0[1]=q0.y; bq0[2]=q0.z; bq0[3]=q0.w;
        bq1[0]=q1.x; bq1[1]=q1.y; bq1[2]=q1.z; bq1[3]=q1.w;
      }

#define STEP(T, BDIAG, BUP) do {                                            \
        float s1 = wshr1(cur);                                              \
        if (lane == 0) {                                                    \
          if (w == 0) { s1 = BIGV; s2 = (p == 0 && (T) == 0) ? 0.f : BIGV; }\
          else        { s1 = (BUP); s2 = (BDIAG); }                         \
        }                                                                   \
        int jl = (T) - lane;                                                \
        bool valid = (unsigned)jl < 32u;                                    \
        float dv = d0; d0 = d1; d1 = d2;                                    \
        { int jc = ((T) + 3 - lane) & 31;                                   \
          d2 = DtW[jc * DCS + lane]; }                                      \
        float m = fminf(s2, fminf(s1, cur));                                \
        float e0 = fexp2((m - s2)  * C2);                                   \
        float e1 = fexp2((m - s1)  * C2);                                   \
        float e2 = fexp2((m - cur) * C2);                                   \
        float val = dv + fmaf(-L2C, flog2(e0 + e1 + e2), m);                \
        s2 = s1;                                                            \
        if ((T) == tstar) extv = val;                                       \
        if (valid) {                                                        \
          cur = val;                                                        \
          if (wr63) bndW[jl + 1] = val;                                     \
        }                                                                   \
      } while (0)

      for (int tq = 0; tq < 24; ++tq) {
        const int tb = tq * 4;
        float bq2[4];
        if (w > 0) {
          int off = tb + 8; off = off > 32 ? 32 : off;
          float4 q = *(const float4*)&bndR[off];
          bq2[0]=q.x; bq2[1]=q.y; bq2[2]=q.z; bq2[3]=q.w;
        }
        STEP(tb + 0, bq0[0], bq0[1]);
        STEP(tb + 1, bq0[1], bq0[2]);
        STEP(tb + 2, bq0[2], bq0[3]);
        STEP(tb + 3, bq0[3], bq1[0]);
        bq0[0]=bq1[0]; bq0[1]=bq1[1]; bq0[2]=bq1[2]; bq0[3]=bq1[3];
        bq1[0]=bq2[0]; bq1[1]=bq2[1]; bq1[2]=bq2[2]; bq1[3]=bq2[3];
      }
#undef STEP
      if (w == wt && r == rstar && lane == it) dist[p_id] = extv * invLen;
      leftR = cur;            // R[row][32p+32] -> next panel's left boundary
    }
  }
}

// ---------------------------------------------------------------------------
// Loss reduction over 16 windows (validated rounds 1-2).
// ---------------------------------------------------------------------------
__device__ __forceinline__ float median5(const float* v) {
#pragma unroll
  for (int i = 0; i < 5; ++i) {
    int c = 0;
#pragma unroll
    for (int j = 0; j < 5; ++j)
      c += (v[j] < v[i]) || ((v[j] == v[i]) && (j < i));
    if (c == 2) return v[i];
  }
  return v[0];
}

__global__ void loss_kernel(const float* __restrict__ dist, float* __restrict__ out) {
  __shared__ float acc[NWIN];
  const int w = threadIdx.x;
  if (w < NWIN) {
    float dg[5], dn[10];
#pragma unroll
    for (int g = 0; g < 5; ++g)  dg[g] = dist[w * PERW + g];
#pragma unroll
    for (int n = 0; n < 10; ++n) dn[n] = dist[w * PERW + 5 + n];

    float lk = 0.f; int nz = 0;
#pragma unroll
    for (int g = 0; g < 5; ++g)
#pragma unroll
      for (int n = 0; n < 10; ++n) {
        float t = dg[g] + 1.0f - dn[n];
        if (t > 0.f) { lk += t; ++nz; }
      }
    float lv = lk / (1.0f + (float)nz);

    float sp = 0.f;
#pragma unroll
    for (int g = 0; g < 5; ++g) sp += dg[g];
    float only_pos = sp * (0.01f / 5.0f);

    float mg = median5(dg);
    float ms = median5(dn);

    int err = 0;
#pragma unroll
    for (int g = 0; g < 5; ++g) {
      err += ((dg[g] < mg) && (dn[g] < mg));
      err += ((dg[g] > ms) && (dn[g] > ms));
      err += ((dg[g] < mg) && (dn[5 + g] < mg));
      err += ((dg[g] > ms) && (dn[5 + g] > ms));
    }
    float offset = (float)err * (1.0f / 50.0f);

    acc[w] = lv + only_pos + offset;
  }
  __syncthreads();
  if (w == 0) {
    float s = 0.f;
#pragma unroll
    for (int i = 0; i < NWIN; ++i) s += acc[i];
    out[0] = s / (float)NWIN;
  }
}

// ---------------------------------------------------------------------------
extern "C" void kernel_launch(void* const* d_in, const int* in_sizes, int n_in,
                              void* d_out, int out_size, void* d_ws, size_t ws_size,
                              hipStream_t stream) {
  const float* data = (const float*)d_in[0];
  const int* lens   = (const int*)d_in[1];
  float* dist = (float*)d_ws;

  sdtw_kernel<<<NPAIR, LQ, 0, stream>>>(data, lens, dist);
  loss_kernel<<<1, 64, 0, stream>>>(dist, (float*)d_out);
}